// Round 2
// baseline (860.592 us; speedup 1.0000x reference)
//
#include <hip/hip_runtime.h>
#include <stdint.h>

typedef __attribute__((ext_vector_type(8))) __bf16 bf16x8;
typedef __attribute__((ext_vector_type(4))) float f32x4;

#define DEVI static __device__ __forceinline__

DEVI uint16_t f2b(float f) {
  uint32_t u = __float_as_uint(f);
  u += 0x7FFFu + ((u >> 16) & 1u);
  return (uint16_t)(u >> 16);
}
DEVI float b2f(uint16_t b) { return __uint_as_float(((uint32_t)b) << 16); }

DEVI void gl_lds16(const void* g, void* l) {
  __builtin_amdgcn_global_load_lds((const __attribute__((address_space(1))) void*)g,
                                   (__attribute__((address_space(3))) void*)l, 16, 0, 0);
}

DEVI f32x4 mfma16(bf16x8 a, bf16x8 b, f32x4 c) {
  return __builtin_amdgcn_mfma_f32_16x16x32_bf16(a, b, c, 0, 0, 0);
}

// ---------------- cast x fp32 -> bf16 ----------------
__global__ void cast_kernel(const float* __restrict__ X, uint16_t* __restrict__ Y) {
  int id = blockIdx.x * 256 + threadIdx.x;
  float4 v = ((const float4*)X)[id];
  uint16_t o[4] = {f2b(v.x), f2b(v.y), f2b(v.z), f2b(v.w)};
  *(uint64_t*)&Y[(size_t)id * 4] = *(uint64_t*)o;
}

// ------------- weight transpose+cast+pad: W[Kw][Nw] f32 -> Wt[Np][Kp] bf16 -------------
__global__ void wt_kernel(const float* __restrict__ W, uint16_t* __restrict__ Wt,
                          int Kw, int Nw, int Kp, int Np) {
  __shared__ uint16_t T[64][72];
  const int t = threadIdx.x;
  const int n0 = blockIdx.x * 64, k0 = blockIdx.y * 64;
#pragma unroll
  for (int p = 0; p < 2; ++p) {
    int r = p * 32 + (t >> 3);
    int c0 = (t & 7) * 8;
    int gr = k0 + r;
#pragma unroll
    for (int e = 0; e < 8; ++e) {
      int gc = n0 + c0 + e;
      float v = (gr < Kw && gc < Nw) ? W[(size_t)gr * Nw + gc] : 0.f;
      T[c0 + e][r] = f2b(v);
    }
  }
  __syncthreads();
#pragma unroll
  for (int p = 0; p < 2; ++p) {
    int dr = p * 32 + (t >> 3);
    int mc = (t & 7) * 8;
    uint16_t tmp[8];
#pragma unroll
    for (int e = 0; e < 8; ++e) tmp[e] = T[dr][mc + e];
    *(uint64_t*)&Wt[(size_t)(n0 + dr) * Kp + k0 + mc] = ((uint64_t*)tmp)[0];
    *(uint64_t*)&Wt[(size_t)(n0 + dr) * Kp + k0 + mc + 4] = ((uint64_t*)tmp)[1];
  }
}

// ---------------- GEMM: C[M][N] = A[M][K] * Bt[N][K]^T  (bf16 in, bf16/f32 out) ----------------
template <bool F32OUT>
__global__ __launch_bounds__(256) void gemm_bt(const uint16_t* __restrict__ A,
                                               const uint16_t* __restrict__ Bt,
                                               void* __restrict__ Cv,
                                               int M, int N, int K) {
  __shared__ uint16_t As[128 * 32];
  __shared__ uint16_t Bs[128 * 32];
  const int tid = threadIdx.x;
  const int lane = tid & 63;
  const int lr = lane & 15, lg = lane >> 4;
  const int wid = tid >> 6;
  const int wr = (wid >> 1) * 64, wc = (wid & 1) * 64;
  const size_t row0 = (size_t)blockIdx.y * 128, col0 = (size_t)blockIdx.x * 128;
  const uint16_t* Ag = A + row0 * K;
  const uint16_t* Bg = Bt + col0 * K;
  f32x4 acc[4][4] = {};
  for (int k0 = 0; k0 < K; k0 += 32) {
    __syncthreads();
#pragma unroll
    for (int i = 0; i < 2; ++i) {
      int c = i * 256 + tid;
      gl_lds16(Ag + (size_t)(c >> 2) * K + k0 + (c & 3) * 8,
               &As[(size_t)(i * 256 + (tid & 0xC0)) * 8]);
    }
#pragma unroll
    for (int i = 0; i < 2; ++i) {
      int c = i * 256 + tid;
      gl_lds16(Bg + (size_t)(c >> 2) * K + k0 + (c & 3) * 8,
               &Bs[(size_t)(i * 256 + (tid & 0xC0)) * 8]);
    }
    __syncthreads();
    bf16x8 af[4], bfr[4];
#pragma unroll
    for (int m = 0; m < 4; ++m) af[m] = *(const bf16x8*)&As[(wr + m * 16 + lr) * 32 + lg * 8];
#pragma unroll
    for (int n = 0; n < 4; ++n) bfr[n] = *(const bf16x8*)&Bs[(wc + n * 16 + lr) * 32 + lg * 8];
#pragma unroll
    for (int m = 0; m < 4; ++m)
#pragma unroll
      for (int n = 0; n < 4; ++n) acc[m][n] = mfma16(af[m], bfr[n], acc[m][n]);
  }
#pragma unroll
  for (int m = 0; m < 4; ++m)
#pragma unroll
    for (int n = 0; n < 4; ++n)
#pragma unroll
      for (int j = 0; j < 4; ++j) {
        size_t row = row0 + wr + m * 16 + lg * 4 + j;
        size_t col = col0 + wc + n * 16 + lr;
        if (F32OUT)
          ((float*)Cv)[row * N + col] = acc[m][n][j];
        else
          ((uint16_t*)Cv)[row * N + col] = f2b(acc[m][n][j]);
      }
}

// ---------------- RoPE ----------------
__global__ void rope_k_kernel(uint16_t* __restrict__ kr) {  // rows 4096, stride 128, first 64 cols
  int id = blockIdx.x * 256 + threadIdx.x;  // 4096*32
  int row = id >> 5, i = id & 31;
  int pos = row & 2047;
  float invf = exp2f(-13.287712379549449f * (float)i / 32.f);
  float ang = (float)pos * invf;
  float s, c;
  sincosf(ang, &s, &c);
  size_t base = (size_t)row * 128 + 2 * i;
  float x1 = b2f(kr[base]), x2 = b2f(kr[base + 1]);
  kr[base] = f2b(x1 * c - x2 * s);
  kr[base + 1] = f2b(x1 * s + x2 * c);
}

__global__ void rope_q_kernel(uint16_t* __restrict__ qr) {  // rows 4096, 16 heads x 64
  int id = blockIdx.x * 256 + threadIdx.x;  // 4096*512
  int row = id >> 9;
  int rem = id & 511;
  int h = rem >> 5, i = rem & 31;
  int pos = row & 2047;
  float invf = exp2f(-13.287712379549449f * (float)i / 32.f);
  float ang = (float)pos * invf;
  float s, c;
  sincosf(ang, &s, &c);
  size_t base = (size_t)row * 1024 + h * 64 + 2 * i;
  float x1 = b2f(qr[base]), x2 = b2f(qr[base + 1]);
  qr[base] = f2b(x1 * c - x2 * s);
  qr[base + 1] = f2b(x1 * s + x2 * c);
}

// ---------------- V transpose: v(4096, 16*128) -> vt(b,h,128,2048) ----------------
__global__ void vtrans_kernel(const uint16_t* __restrict__ v, uint16_t* __restrict__ vt) {
  __shared__ uint16_t T[64][72];
  const int t = threadIdx.x;
  const int mt = blockIdx.x, dt = blockIdx.y, bh = blockIdx.z;
  const int b = bh >> 4, h = bh & 15;
  const int m0 = mt * 64, d0 = dt * 64;
#pragma unroll
  for (int p = 0; p < 2; ++p) {
    int r = p * 32 + (t >> 3), c8 = (t & 7) * 8;
    const uint16_t* s = &v[((size_t)(b * 2048 + m0 + r)) * 2048 + h * 128 + d0 + c8];
    uint16_t tmp[8];
    ((uint64_t*)tmp)[0] = ((const uint64_t*)s)[0];
    ((uint64_t*)tmp)[1] = ((const uint64_t*)s)[1];
#pragma unroll
    for (int e = 0; e < 8; ++e) T[c8 + e][r] = tmp[e];
  }
  __syncthreads();
#pragma unroll
  for (int p = 0; p < 2; ++p) {
    int dr = p * 32 + (t >> 3), mc = (t & 7) * 8;
    uint16_t tmp[8];
#pragma unroll
    for (int e = 0; e < 8; ++e) tmp[e] = T[dr][mc + e];
    uint16_t* dstp = &vt[((size_t)(bh * 128 + d0 + dr)) * 2048 + m0 + mc];
    ((uint64_t*)dstp)[0] = ((uint64_t*)tmp)[0];
    ((uint64_t*)dstp)[1] = ((uint64_t*)tmp)[1];
  }
}

// ---------------- causal flash attention, barrier-free, global-direct K/V ----------------
// qc: (4096, 2048) head-major cols; qrp: (4096, 1024); kc: (4096, 2048); krp: (4096, 128);
// vt: (b,h,128,2048); obuf: (4096, 2048)
// Block: 4 waves x 16 q-rows = 64-row Q tile. Block handles Q-tiles pairi and 31-pairi
// (uniform 33 KV-tile iterations). No __syncthreads anywhere; P relayout via per-wave LDS.
__global__ __launch_bounds__(256) void attn_kernel(const uint16_t* __restrict__ qc,
                                                   const uint16_t* __restrict__ qrp,
                                                   const uint16_t* __restrict__ kc,
                                                   const uint16_t* __restrict__ krp,
                                                   const uint16_t* __restrict__ vt,
                                                   uint16_t* __restrict__ obuf) {
  __shared__ uint16_t Ps[4 * 16 * 64];  // 8KB, per-wave P relayout, XOR-swizzled
  const int tid = threadIdx.x;
  const int wid = tid >> 6, lane = tid & 63;
  const int lr = lane & 15, lg = lane >> 4;
  const int pairi = blockIdx.x, h = blockIdx.y, b = blockIdx.z;
  const int bh = b * 16 + h;
  const float sc2 = 0.07216878364870323f * 1.4426950408889634f;

  const char* Kcb = (const char*)kc + (size_t)b * 2048 * 4096 + h * 256;
  const char* Krb = (const char*)krp + (size_t)b * 2048 * 256;
  const char* Vb = (const char*)vt + (size_t)bh * 128 * 4096;
  char* PwB = (char*)(Ps + wid * 1024);

  for (int ph = 0; ph < 2; ++ph) {
    const int qt = ph ? (31 - pairi) : pairi;
    const int q0 = qt * 64;
    const int qrow = q0 + wid * 16 + lr;
    bf16x8 qf[6];
    {
      const char* Qcp = (const char*)qc + (size_t)(b * 2048 + qrow) * 4096 + h * 256 + lg * 16;
      const char* Qrp = (const char*)qrp + (size_t)(b * 2048 + qrow) * 2048 + h * 128 + lg * 16;
#pragma unroll
      for (int kb = 0; kb < 4; ++kb) qf[kb] = *(const bf16x8*)(Qcp + kb * 64);
#pragma unroll
      for (int kb = 0; kb < 2; ++kb) qf[4 + kb] = *(const bf16x8*)(Qrp + kb * 64);
    }
    f32x4 o[8] = {};
    float mrun[4], lrun[4];
#pragma unroll
    for (int j = 0; j < 4; ++j) { mrun[j] = -INFINITY; lrun[j] = 0.f; }

    for (int t = 0; t <= qt; ++t) {
      // S = Q K^T : K B-fragments straight from global (L1/L2-resident)
      f32x4 s[4] = {};
      const char* KcT = Kcb + (size_t)t * 64 * 4096 + lg * 16;
      const char* KrT = Krb + (size_t)t * 64 * 256 + lg * 16;
#pragma unroll
      for (int n = 0; n < 4; ++n) {
        int r = n * 16 + lr;
        const char* kcp = KcT + (size_t)r * 4096;
        const char* krr = KrT + (size_t)r * 256;
#pragma unroll
        for (int kb = 0; kb < 4; ++kb)
          s[n] = mfma16(qf[kb], *(const bf16x8*)(kcp + kb * 64), s[n]);
        s[n] = mfma16(qf[4], *(const bf16x8*)(krr), s[n]);
        s[n] = mfma16(qf[5], *(const bf16x8*)(krr + 64), s[n]);
      }
      if (t == qt) {
#pragma unroll
        for (int n = 0; n < 4; ++n)
#pragma unroll
          for (int j = 0; j < 4; ++j)
            if (t * 64 + n * 16 + lr > q0 + wid * 16 + lg * 4 + j) s[n][j] = -INFINITY;
      }
      // online softmax (16-lane-group shfl reductions)
      float pm[4];
#pragma unroll
      for (int j = 0; j < 4; ++j) {
        float v = fmaxf(fmaxf(s[0][j], s[1][j]), fmaxf(s[2][j], s[3][j]));
        v = fmaxf(v, __shfl_xor(v, 1));
        v = fmaxf(v, __shfl_xor(v, 2));
        v = fmaxf(v, __shfl_xor(v, 4));
        v = fmaxf(v, __shfl_xor(v, 8));
        pm[j] = v;
      }
      float alpha[4];
#pragma unroll
      for (int j = 0; j < 4; ++j) {
        float mn = fmaxf(mrun[j], pm[j]);
        alpha[j] = exp2f((mrun[j] - mn) * sc2);
        mrun[j] = mn;
        lrun[j] *= alpha[j];
      }
#pragma unroll
      for (int n2 = 0; n2 < 8; ++n2)
#pragma unroll
        for (int j = 0; j < 4; ++j) o[n2][j] *= alpha[j];
      float rs[4] = {0.f, 0.f, 0.f, 0.f};
#pragma unroll
      for (int n = 0; n < 4; ++n)
#pragma unroll
        for (int j = 0; j < 4; ++j) {
          float p = exp2f((s[n][j] - mrun[j]) * sc2);
          rs[j] += p;
          int row = lg * 4 + j;
          *(uint16_t*)(PwB + row * 128 + ((((n * 16 + lr)) * 2) ^ ((row & 7) << 4))) = f2b(p);
        }
#pragma unroll
      for (int j = 0; j < 4; ++j) {
        float v = rs[j];
        v += __shfl_xor(v, 1);
        v += __shfl_xor(v, 2);
        v += __shfl_xor(v, 4);
        v += __shfl_xor(v, 8);
        lrun[j] += v;
      }
      // O += P V : V B-fragments straight from vt (no staging)
#pragma unroll
      for (int kb2 = 0; kb2 < 2; ++kb2) {
        bf16x8 pa = *(const bf16x8*)(PwB + lr * 128 + ((kb2 * 64 + lg * 16) ^ ((lr & 7) << 4)));
#pragma unroll
        for (int n2 = 0; n2 < 8; ++n2) {
          const char* vp = Vb + (size_t)(n2 * 16 + lr) * 4096 + t * 128 + kb2 * 64 + lg * 16;
          o[n2] = mfma16(pa, *(const bf16x8*)vp, o[n2]);
        }
      }
    }
    float inv[4];
#pragma unroll
    for (int j = 0; j < 4; ++j) inv[j] = 1.f / lrun[j];
#pragma unroll
    for (int n2 = 0; n2 < 8; ++n2)
#pragma unroll
      for (int j = 0; j < 4; ++j) {
        size_t row = (size_t)b * 2048 + q0 + wid * 16 + lg * 4 + j;
        size_t col = (size_t)h * 128 + n2 * 16 + lr;
        obuf[row * 2048 + col] = f2b(o[n2][j] * inv[j]);
      }
  }
}

// ---------------- workspace layout (bf16 elements) ----------------
static constexpr size_t OFF_XB = 0;                      // 4096x2048 (later reused as OBUF)
static constexpr size_t OFF_WDKV = 8388608;              // 768x2048
static constexpr size_t OFF_WUK = OFF_WDKV + 1572864;    // 2048x768
static constexpr size_t OFF_WUV = OFF_WUK + 1572864;     // 2048x768
static constexpr size_t OFF_WDQ = OFF_WUV + 1572864;     // 768x2048
static constexpr size_t OFF_WUQ = OFF_WDQ + 1572864;     // 2048x768
static constexpr size_t OFF_WQR = OFF_WUQ + 1572864;     // 1024x768
static constexpr size_t OFF_WKR = OFF_WQR + 786432;      // 128x2048
static constexpr size_t OFF_WO = OFF_WKR + 262144;       // 2048x2048
static constexpr size_t OFF_CKV = OFF_WO + 4194304;      // 4096x768
static constexpr size_t OFF_CQ = OFF_CKV + 3145728;      // 4096x768
static constexpr size_t OFF_KC = OFF_CQ + 3145728;       // 4096x2048
static constexpr size_t OFF_VBUF = OFF_KC + 8388608;     // 4096x2048
static constexpr size_t OFF_QC = OFF_VBUF + 8388608;     // 4096x2048
static constexpr size_t OFF_KRP = OFF_QC + 8388608;      // 4096x128
static constexpr size_t OFF_QRP = OFF_KRP + 524288;      // 4096x1024
static constexpr size_t OFF_VT = OFF_QRP + 4194304;      // 2*16*128*2048
// total = OFF_VT + 8388608 = 66,060,288 elems * 2B = ~132 MB

extern "C" void kernel_launch(void* const* d_in, const int* in_sizes, int n_in,
                              void* d_out, int out_size, void* d_ws, size_t ws_size,
                              hipStream_t stream) {
  (void)in_sizes; (void)n_in; (void)out_size; (void)ws_size;
  const float* x = (const float*)d_in[0];
  const float* Wdkv = (const float*)d_in[1];
  const float* Wuk = (const float*)d_in[2];
  const float* Wuv = (const float*)d_in[3];
  const float* Wkr = (const float*)d_in[4];
  const float* Wdq = (const float*)d_in[5];
  const float* Wuq = (const float*)d_in[6];
  const float* Wqr = (const float*)d_in[7];
  const float* Wo = (const float*)d_in[8];
  uint16_t* ws = (uint16_t*)d_ws;

  uint16_t* xb = ws + OFF_XB;
  uint16_t* obuf = ws + OFF_XB;  // reuse after x dead
  uint16_t* wdkv = ws + OFF_WDKV;
  uint16_t* wuk = ws + OFF_WUK;
  uint16_t* wuv = ws + OFF_WUV;
  uint16_t* wdq = ws + OFF_WDQ;
  uint16_t* wuq = ws + OFF_WUQ;
  uint16_t* wqr = ws + OFF_WQR;
  uint16_t* wkr = ws + OFF_WKR;
  uint16_t* wo = ws + OFF_WO;
  uint16_t* ckv = ws + OFF_CKV;
  uint16_t* cq = ws + OFF_CQ;
  uint16_t* kc = ws + OFF_KC;
  uint16_t* vbuf = ws + OFF_VBUF;
  uint16_t* qc = ws + OFF_QC;
  uint16_t* krp = ws + OFF_KRP;
  uint16_t* qrp = ws + OFF_QRP;
  uint16_t* vtb = ws + OFF_VT;

  // 1. cast x
  cast_kernel<<<8192, 256, 0, stream>>>(x, xb);
  // 2. weight transpose+cast+pad
  wt_kernel<<<dim3(12, 32), 256, 0, stream>>>(Wdkv, wdkv, 2048, 682, 2048, 768);
  wt_kernel<<<dim3(32, 12), 256, 0, stream>>>(Wuk, wuk, 682, 2048, 768, 2048);
  wt_kernel<<<dim3(32, 12), 256, 0, stream>>>(Wuv, wuv, 682, 2048, 768, 2048);
  wt_kernel<<<dim3(12, 32), 256, 0, stream>>>(Wdq, wdq, 2048, 682, 2048, 768);
  wt_kernel<<<dim3(32, 12), 256, 0, stream>>>(Wuq, wuq, 682, 2048, 768, 2048);
  wt_kernel<<<dim3(16, 12), 256, 0, stream>>>(Wqr, wqr, 682, 1024, 768, 1024);
  wt_kernel<<<dim3(2, 32), 256, 0, stream>>>(Wkr, wkr, 2048, 64, 2048, 128);
  wt_kernel<<<dim3(32, 32), 256, 0, stream>>>(Wo, wo, 2048, 2048, 2048, 2048);
  // 3. down projections from x
  gemm_bt<false><<<dim3(6, 32), 256, 0, stream>>>(xb, wdkv, ckv, 4096, 768, 2048);
  gemm_bt<false><<<dim3(6, 32), 256, 0, stream>>>(xb, wdq, cq, 4096, 768, 2048);
  gemm_bt<false><<<dim3(1, 32), 256, 0, stream>>>(xb, wkr, krp, 4096, 128, 2048);
  // 4. up projections
  gemm_bt<false><<<dim3(16, 32), 256, 0, stream>>>(ckv, wuk, kc, 4096, 2048, 768);
  gemm_bt<false><<<dim3(16, 32), 256, 0, stream>>>(ckv, wuv, vbuf, 4096, 2048, 768);
  gemm_bt<false><<<dim3(16, 32), 256, 0, stream>>>(cq, wuq, qc, 4096, 2048, 768);
  gemm_bt<false><<<dim3(8, 32), 256, 0, stream>>>(cq, wqr, qrp, 4096, 1024, 768);
  // 5. rope
  rope_k_kernel<<<512, 256, 0, stream>>>(krp);
  rope_q_kernel<<<8192, 256, 0, stream>>>(qrp);
  // 6. V transpose
  vtrans_kernel<<<dim3(32, 2, 32), 256, 0, stream>>>(vbuf, vtb);
  // 7. attention (barrier-free, direct K/V; obuf overwrites xb region -- xb dead)
  attn_kernel<<<dim3(16, 16, 2), 256, 0, stream>>>(qc, qrp, kc, krp, vtb, obuf);
  // 8. output projection -> d_out fp32
  gemm_bt<true><<<dim3(16, 32), 256, 0, stream>>>(obuf, wo, d_out, 4096, 2048, 2048);
}

// Round 3
// 514.044 us; speedup vs baseline: 1.6742x; 1.6742x over previous
//
#include <hip/hip_runtime.h>
#include <stdint.h>

typedef __attribute__((ext_vector_type(8))) __bf16 bf16x8;
typedef __attribute__((ext_vector_type(4))) float f32x4;

#define DEVI static __device__ __forceinline__

DEVI uint16_t f2b(float f) {
  uint32_t u = __float_as_uint(f);
  u += 0x7FFFu + ((u >> 16) & 1u);
  return (uint16_t)(u >> 16);
}
DEVI float b2f(uint16_t b) { return __uint_as_float(((uint32_t)b) << 16); }

DEVI void gl_lds16(const void* g, void* l) {
  __builtin_amdgcn_global_load_lds((const __attribute__((address_space(1))) void*)g,
                                   (__attribute__((address_space(3))) void*)l, 16, 0, 0);
}

DEVI f32x4 mfma16(bf16x8 a, bf16x8 b, f32x4 c) {
  return __builtin_amdgcn_mfma_f32_16x16x32_bf16(a, b, c, 0, 0, 0);
}

// ---------------- cast x fp32 -> bf16 ----------------
__global__ void cast_kernel(const float* __restrict__ X, uint16_t* __restrict__ Y) {
  int id = blockIdx.x * 256 + threadIdx.x;
  float4 v = ((const float4*)X)[id];
  uint16_t o[4] = {f2b(v.x), f2b(v.y), f2b(v.z), f2b(v.w)};
  *(uint64_t*)&Y[(size_t)id * 4] = *(uint64_t*)o;
}

// ------------- weight transpose+cast+pad: W[Kw][Nw] f32 -> Wt[Np][Kp] bf16 -------------
__global__ void wt_kernel(const float* __restrict__ W, uint16_t* __restrict__ Wt,
                          int Kw, int Nw, int Kp, int Np) {
  __shared__ uint16_t T[64][72];
  const int t = threadIdx.x;
  const int n0 = blockIdx.x * 64, k0 = blockIdx.y * 64;
#pragma unroll
  for (int p = 0; p < 2; ++p) {
    int r = p * 32 + (t >> 3);
    int c0 = (t & 7) * 8;
    int gr = k0 + r;
#pragma unroll
    for (int e = 0; e < 8; ++e) {
      int gc = n0 + c0 + e;
      float v = (gr < Kw && gc < Nw) ? W[(size_t)gr * Nw + gc] : 0.f;
      T[c0 + e][r] = f2b(v);
    }
  }
  __syncthreads();
#pragma unroll
  for (int p = 0; p < 2; ++p) {
    int dr = p * 32 + (t >> 3);
    int mc = (t & 7) * 8;
    uint16_t tmp[8];
#pragma unroll
    for (int e = 0; e < 8; ++e) tmp[e] = T[dr][mc + e];
    *(uint64_t*)&Wt[(size_t)(n0 + dr) * Kp + k0 + mc] = ((uint64_t*)tmp)[0];
    *(uint64_t*)&Wt[(size_t)(n0 + dr) * Kp + k0 + mc + 4] = ((uint64_t*)tmp)[1];
  }
}

// ---------------- GEMM: C[M][N] = A[M][K] * Bt[N][K]^T  (bf16 in, bf16/f32 out) ----------------
template <bool F32OUT>
__global__ __launch_bounds__(256) void gemm_bt(const uint16_t* __restrict__ A,
                                               const uint16_t* __restrict__ Bt,
                                               void* __restrict__ Cv,
                                               int M, int N, int K) {
  __shared__ uint16_t As[128 * 32];
  __shared__ uint16_t Bs[128 * 32];
  const int tid = threadIdx.x;
  const int lane = tid & 63;
  const int lr = lane & 15, lg = lane >> 4;
  const int wid = tid >> 6;
  const int wr = (wid >> 1) * 64, wc = (wid & 1) * 64;
  const size_t row0 = (size_t)blockIdx.y * 128, col0 = (size_t)blockIdx.x * 128;
  const uint16_t* Ag = A + row0 * K;
  const uint16_t* Bg = Bt + col0 * K;
  f32x4 acc[4][4] = {};
  for (int k0 = 0; k0 < K; k0 += 32) {
    __syncthreads();
#pragma unroll
    for (int i = 0; i < 2; ++i) {
      int c = i * 256 + tid;
      gl_lds16(Ag + (size_t)(c >> 2) * K + k0 + (c & 3) * 8,
               &As[(size_t)(i * 256 + (tid & 0xC0)) * 8]);
    }
#pragma unroll
    for (int i = 0; i < 2; ++i) {
      int c = i * 256 + tid;
      gl_lds16(Bg + (size_t)(c >> 2) * K + k0 + (c & 3) * 8,
               &Bs[(size_t)(i * 256 + (tid & 0xC0)) * 8]);
    }
    __syncthreads();
    bf16x8 af[4], bfr[4];
#pragma unroll
    for (int m = 0; m < 4; ++m) af[m] = *(const bf16x8*)&As[(wr + m * 16 + lr) * 32 + lg * 8];
#pragma unroll
    for (int n = 0; n < 4; ++n) bfr[n] = *(const bf16x8*)&Bs[(wc + n * 16 + lr) * 32 + lg * 8];
#pragma unroll
    for (int m = 0; m < 4; ++m)
#pragma unroll
      for (int n = 0; n < 4; ++n) acc[m][n] = mfma16(af[m], bfr[n], acc[m][n]);
  }
#pragma unroll
  for (int m = 0; m < 4; ++m)
#pragma unroll
    for (int n = 0; n < 4; ++n)
#pragma unroll
      for (int j = 0; j < 4; ++j) {
        size_t row = row0 + wr + m * 16 + lg * 4 + j;
        size_t col = col0 + wc + n * 16 + lr;
        if (F32OUT)
          ((float*)Cv)[row * N + col] = acc[m][n][j];
        else
          ((uint16_t*)Cv)[row * N + col] = f2b(acc[m][n][j]);
      }
}

// ---------------- RoPE ----------------
__global__ void rope_k_kernel(uint16_t* __restrict__ kr) {
  int id = blockIdx.x * 256 + threadIdx.x;  // 4096*32
  int row = id >> 5, i = id & 31;
  int pos = row & 2047;
  float invf = exp2f(-13.287712379549449f * (float)i / 32.f);
  float ang = (float)pos * invf;
  float s, c;
  sincosf(ang, &s, &c);
  size_t base = (size_t)row * 128 + 2 * i;
  float x1 = b2f(kr[base]), x2 = b2f(kr[base + 1]);
  kr[base] = f2b(x1 * c - x2 * s);
  kr[base + 1] = f2b(x1 * s + x2 * c);
}

__global__ void rope_q_kernel(uint16_t* __restrict__ qr) {
  int id = blockIdx.x * 256 + threadIdx.x;  // 4096*512
  int row = id >> 9;
  int rem = id & 511;
  int h = rem >> 5, i = rem & 31;
  int pos = row & 2047;
  float invf = exp2f(-13.287712379549449f * (float)i / 32.f);
  float ang = (float)pos * invf;
  float s, c;
  sincosf(ang, &s, &c);
  size_t base = (size_t)row * 1024 + h * 64 + 2 * i;
  float x1 = b2f(qr[base]), x2 = b2f(qr[base + 1]);
  qr[base] = f2b(x1 * c - x2 * s);
  qr[base + 1] = f2b(x1 * s + x2 * c);
}

// ---------------- V transpose: v(4096, 16*128) -> vt(b,h,128,2048) ----------------
__global__ void vtrans_kernel(const uint16_t* __restrict__ v, uint16_t* __restrict__ vt) {
  __shared__ uint16_t T[64][72];
  const int t = threadIdx.x;
  const int mt = blockIdx.x, dt = blockIdx.y, bh = blockIdx.z;
  const int b = bh >> 4, h = bh & 15;
  const int m0 = mt * 64, d0 = dt * 64;
#pragma unroll
  for (int p = 0; p < 2; ++p) {
    int r = p * 32 + (t >> 3), c8 = (t & 7) * 8;
    const uint16_t* s = &v[((size_t)(b * 2048 + m0 + r)) * 2048 + h * 128 + d0 + c8];
    uint16_t tmp[8];
    ((uint64_t*)tmp)[0] = ((const uint64_t*)s)[0];
    ((uint64_t*)tmp)[1] = ((const uint64_t*)s)[1];
#pragma unroll
    for (int e = 0; e < 8; ++e) T[c8 + e][r] = tmp[e];
  }
  __syncthreads();
#pragma unroll
  for (int p = 0; p < 2; ++p) {
    int dr = p * 32 + (t >> 3), mc = (t & 7) * 8;
    uint16_t tmp[8];
#pragma unroll
    for (int e = 0; e < 8; ++e) tmp[e] = T[dr][mc + e];
    uint16_t* dstp = &vt[((size_t)(bh * 128 + d0 + dr)) * 2048 + m0 + mc];
    ((uint64_t*)dstp)[0] = ((uint64_t*)tmp)[0];
    ((uint64_t*)dstp)[1] = ((uint64_t*)tmp)[1];
  }
}

// ---------------- causal flash attention ----------------
// 8 waves/block, 128-row Q tile, KVBLK=64. K (kc|krp interleaved, 384B rows, XOR-swz)
// double-buffered in LDS; V prefetched to registers from vt; P via per-wave LDS.
// Paired Q-tiles (qt, 15-qt) for uniform work; XCD-swizzled block ids for L2 locality.
DEVI void stage_k(const char* Kcb, const char* Krb, char* dst, int t, int tid) {
#pragma unroll
  for (int i = 0; i < 3; ++i) {
    int c = i * 512 + tid;
    int r = c / 24;
    int wb = (c % 24) * 16;
    int wb2 = wb ^ ((r & 7) << 4);
    const char* src = (wb2 < 256)
                          ? Kcb + (size_t)(t * 64 + r) * 4096 + wb2
                          : Krb + (size_t)(t * 64 + r) * 256 + (wb2 - 256);
    gl_lds16(src, dst + (i * 512 + (tid & 0x1C0)) * 16);
  }
}

__global__ __launch_bounds__(512, 2) void attn_kernel(const uint16_t* __restrict__ qc,
                                                      const uint16_t* __restrict__ qrp,
                                                      const uint16_t* __restrict__ kc,
                                                      const uint16_t* __restrict__ krp,
                                                      const uint16_t* __restrict__ vt,
                                                      uint16_t* __restrict__ obuf) {
  __shared__ uint16_t Ks[2][64 * 192];  // 2 x 24KB
  __shared__ uint16_t Ps[8 * 16 * 64];  // 16KB
  const int tid = threadIdx.x;
  const int wid = tid >> 6, lane = tid & 63;
  const int lr = lane & 15, lg = lane >> 4;
  // XCD swizzle: 256 blocks -> 8 XCD chunks of 32 (4 complete (b,h) groups each)
  const int bid = blockIdx.x;
  const int wg = (bid & 7) * 32 + (bid >> 3);
  const int pairi = wg & 7, h = (wg >> 3) & 15, b = wg >> 7;
  const int bh = b * 16 + h;
  const float sc2 = 0.07216878364870323f * 1.4426950408889634f;

  const char* Kcb = (const char*)kc + (size_t)b * 2048 * 4096 + h * 256;
  const char* Krb = (const char*)krp + (size_t)b * 2048 * 256;
  const char* Vb = (const char*)vt + (size_t)bh * 128 * 4096;
  char* PwB = (char*)(Ps + wid * 1024);

  for (int ph = 0; ph < 2; ++ph) {
    const int qt = ph ? (15 - pairi) : pairi;
    const int q0 = qt * 128;
    const int nt = 2 * (qt + 1);
    const int qrow = q0 + wid * 16 + lr;
    bf16x8 qf[6];
    {
      const char* Qcp = (const char*)qc + (size_t)(b * 2048 + qrow) * 4096 + h * 256 + lg * 16;
      const char* Qrp = (const char*)qrp + (size_t)(b * 2048 + qrow) * 2048 + h * 128 + lg * 16;
#pragma unroll
      for (int kb = 0; kb < 4; ++kb) qf[kb] = *(const bf16x8*)(Qcp + kb * 64);
#pragma unroll
      for (int kb = 0; kb < 2; ++kb) qf[4 + kb] = *(const bf16x8*)(Qrp + kb * 64);
    }
    f32x4 o[8] = {};
    float mrun[4], lrun[4];
#pragma unroll
    for (int j = 0; j < 4; ++j) { mrun[j] = -INFINITY; lrun[j] = 0.f; }

    // prologue: stage tile 0
    stage_k(Kcb, Krb, (char*)Ks[0], 0, tid);
    __syncthreads();

    for (int t = 0; t < nt; ++t) {
      const int cur = t & 1;
      if (t + 1 < nt) stage_k(Kcb, Krb, (char*)Ks[cur ^ 1], t + 1, tid);
      const bool active = (t * 64 <= q0 + wid * 16 + 15);
      if (active) {
        const char* KsB = (const char*)Ks[cur];
        f32x4 s[4] = {};
#pragma unroll
        for (int n = 0; n < 4; ++n) {
          int r = n * 16 + lr;
          const char* kp = KsB + r * 384;
          int sw = (r & 7) << 4;
#pragma unroll
          for (int kb = 0; kb < 6; ++kb)
            s[n] = mfma16(qf[kb], *(const bf16x8*)(kp + ((kb * 64 + lg * 16) ^ sw)), s[n]);
        }
        // prefetch V fragments to registers; softmax VALU covers latency
        bf16x8 vf[2][8];
#pragma unroll
        for (int kb2 = 0; kb2 < 2; ++kb2)
#pragma unroll
          for (int n2 = 0; n2 < 8; ++n2)
            vf[kb2][n2] = *(const bf16x8*)(Vb + (size_t)(n2 * 16 + lr) * 4096 + t * 128 +
                                           kb2 * 64 + lg * 16);
        if (t * 64 + 63 > q0 + wid * 16) {
#pragma unroll
          for (int n = 0; n < 4; ++n)
#pragma unroll
            for (int j = 0; j < 4; ++j)
              if (t * 64 + n * 16 + lr > q0 + wid * 16 + lg * 4 + j) s[n][j] = -INFINITY;
        }
        // online softmax with defer-max (THR = 8 on exp2 scale -> 8/sc2 in raw scale)
        float pm[4];
#pragma unroll
        for (int j = 0; j < 4; ++j) {
          float v = fmaxf(fmaxf(s[0][j], s[1][j]), fmaxf(s[2][j], s[3][j]));
          v = fmaxf(v, __shfl_xor(v, 1));
          v = fmaxf(v, __shfl_xor(v, 2));
          v = fmaxf(v, __shfl_xor(v, 4));
          v = fmaxf(v, __shfl_xor(v, 8));
          pm[j] = v;
        }
        bool exceed = false;
#pragma unroll
        for (int j = 0; j < 4; ++j) exceed |= (pm[j] > mrun[j] + 76.8f);
        if (__any(exceed)) {
          float alpha[4];
#pragma unroll
          for (int j = 0; j < 4; ++j) {
            float mn = fmaxf(mrun[j], pm[j]);
            alpha[j] = exp2f((mrun[j] - mn) * sc2);
            mrun[j] = mn;
            lrun[j] *= alpha[j];
          }
#pragma unroll
          for (int n2 = 0; n2 < 8; ++n2)
#pragma unroll
            for (int j = 0; j < 4; ++j) o[n2][j] *= alpha[j];
        }
        float rs[4] = {0.f, 0.f, 0.f, 0.f};
#pragma unroll
        for (int n = 0; n < 4; ++n)
#pragma unroll
          for (int j = 0; j < 4; ++j) {
            float p = exp2f((s[n][j] - mrun[j]) * sc2);
            rs[j] += p;
            int row = lg * 4 + j;
            *(uint16_t*)(PwB + row * 128 + ((((n * 16 + lr)) * 2) ^ ((row & 7) << 4))) = f2b(p);
          }
#pragma unroll
        for (int j = 0; j < 4; ++j) {
          float v = rs[j];
          v += __shfl_xor(v, 1);
          v += __shfl_xor(v, 2);
          v += __shfl_xor(v, 4);
          v += __shfl_xor(v, 8);
          lrun[j] += v;
        }
        // O += P V
#pragma unroll
        for (int kb2 = 0; kb2 < 2; ++kb2) {
          bf16x8 pa = *(const bf16x8*)(PwB + lr * 128 + ((kb2 * 64 + lg * 16) ^ ((lr & 7) << 4)));
#pragma unroll
          for (int n2 = 0; n2 < 8; ++n2) o[n2] = mfma16(pa, vf[kb2][n2], o[n2]);
        }
      }
      __syncthreads();
    }
    float inv[4];
#pragma unroll
    for (int j = 0; j < 4; ++j) inv[j] = 1.f / lrun[j];
#pragma unroll
    for (int n2 = 0; n2 < 8; ++n2)
#pragma unroll
      for (int j = 0; j < 4; ++j) {
        size_t row = (size_t)b * 2048 + q0 + wid * 16 + lg * 4 + j;
        size_t col = (size_t)h * 128 + n2 * 16 + lr;
        obuf[row * 2048 + col] = f2b(o[n2][j] * inv[j]);
      }
  }
}

// ---------------- workspace layout (bf16 elements) ----------------
static constexpr size_t OFF_XB = 0;                      // 4096x2048 (later reused as OBUF)
static constexpr size_t OFF_WDKV = 8388608;              // 768x2048
static constexpr size_t OFF_WUK = OFF_WDKV + 1572864;    // 2048x768
static constexpr size_t OFF_WUV = OFF_WUK + 1572864;     // 2048x768
static constexpr size_t OFF_WDQ = OFF_WUV + 1572864;     // 768x2048
static constexpr size_t OFF_WUQ = OFF_WDQ + 1572864;     // 2048x768
static constexpr size_t OFF_WQR = OFF_WUQ + 1572864;     // 1024x768
static constexpr size_t OFF_WKR = OFF_WQR + 786432;      // 128x2048
static constexpr size_t OFF_WO = OFF_WKR + 262144;       // 2048x2048
static constexpr size_t OFF_CKV = OFF_WO + 4194304;      // 4096x768
static constexpr size_t OFF_CQ = OFF_CKV + 3145728;      // 4096x768
static constexpr size_t OFF_KC = OFF_CQ + 3145728;       // 4096x2048
static constexpr size_t OFF_VBUF = OFF_KC + 8388608;     // 4096x2048
static constexpr size_t OFF_QC = OFF_VBUF + 8388608;     // 4096x2048
static constexpr size_t OFF_KRP = OFF_QC + 8388608;      // 4096x128
static constexpr size_t OFF_QRP = OFF_KRP + 524288;      // 4096x1024
static constexpr size_t OFF_VT = OFF_QRP + 4194304;      // 2*16*128*2048

extern "C" void kernel_launch(void* const* d_in, const int* in_sizes, int n_in,
                              void* d_out, int out_size, void* d_ws, size_t ws_size,
                              hipStream_t stream) {
  (void)in_sizes; (void)n_in; (void)out_size; (void)ws_size;
  const float* x = (const float*)d_in[0];
  const float* Wdkv = (const float*)d_in[1];
  const float* Wuk = (const float*)d_in[2];
  const float* Wuv = (const float*)d_in[3];
  const float* Wkr = (const float*)d_in[4];
  const float* Wdq = (const float*)d_in[5];
  const float* Wuq = (const float*)d_in[6];
  const float* Wqr = (const float*)d_in[7];
  const float* Wo = (const float*)d_in[8];
  uint16_t* ws = (uint16_t*)d_ws;

  uint16_t* xb = ws + OFF_XB;
  uint16_t* obuf = ws + OFF_XB;  // reuse after x dead
  uint16_t* wdkv = ws + OFF_WDKV;
  uint16_t* wuk = ws + OFF_WUK;
  uint16_t* wuv = ws + OFF_WUV;
  uint16_t* wdq = ws + OFF_WDQ;
  uint16_t* wuq = ws + OFF_WUQ;
  uint16_t* wqr = ws + OFF_WQR;
  uint16_t* wkr = ws + OFF_WKR;
  uint16_t* wo = ws + OFF_WO;
  uint16_t* ckv = ws + OFF_CKV;
  uint16_t* cq = ws + OFF_CQ;
  uint16_t* kc = ws + OFF_KC;
  uint16_t* vbuf = ws + OFF_VBUF;
  uint16_t* qc = ws + OFF_QC;
  uint16_t* krp = ws + OFF_KRP;
  uint16_t* qrp = ws + OFF_QRP;
  uint16_t* vtb = ws + OFF_VT;

  cast_kernel<<<8192, 256, 0, stream>>>(x, xb);
  wt_kernel<<<dim3(12, 32), 256, 0, stream>>>(Wdkv, wdkv, 2048, 682, 2048, 768);
  wt_kernel<<<dim3(32, 12), 256, 0, stream>>>(Wuk, wuk, 682, 2048, 768, 2048);
  wt_kernel<<<dim3(32, 12), 256, 0, stream>>>(Wuv, wuv, 682, 2048, 768, 2048);
  wt_kernel<<<dim3(12, 32), 256, 0, stream>>>(Wdq, wdq, 2048, 682, 2048, 768);
  wt_kernel<<<dim3(32, 12), 256, 0, stream>>>(Wuq, wuq, 682, 2048, 768, 2048);
  wt_kernel<<<dim3(16, 12), 256, 0, stream>>>(Wqr, wqr, 682, 1024, 768, 1024);
  wt_kernel<<<dim3(2, 32), 256, 0, stream>>>(Wkr, wkr, 2048, 64, 2048, 128);
  wt_kernel<<<dim3(32, 32), 256, 0, stream>>>(Wo, wo, 2048, 2048, 2048, 2048);
  gemm_bt<false><<<dim3(6, 32), 256, 0, stream>>>(xb, wdkv, ckv, 4096, 768, 2048);
  gemm_bt<false><<<dim3(6, 32), 256, 0, stream>>>(xb, wdq, cq, 4096, 768, 2048);
  gemm_bt<false><<<dim3(1, 32), 256, 0, stream>>>(xb, wkr, krp, 4096, 128, 2048);
  gemm_bt<false><<<dim3(16, 32), 256, 0, stream>>>(ckv, wuk, kc, 4096, 2048, 768);
  gemm_bt<false><<<dim3(16, 32), 256, 0, stream>>>(ckv, wuv, vbuf, 4096, 2048, 768);
  gemm_bt<false><<<dim3(16, 32), 256, 0, stream>>>(cq, wuq, qc, 4096, 2048, 768);
  gemm_bt<false><<<dim3(8, 32), 256, 0, stream>>>(cq, wqr, qrp, 4096, 1024, 768);
  rope_k_kernel<<<512, 256, 0, stream>>>(krp);
  rope_q_kernel<<<8192, 256, 0, stream>>>(qrp);
  vtrans_kernel<<<dim3(32, 2, 32), 256, 0, stream>>>(vbuf, vtb);
  attn_kernel<<<256, 512, 0, stream>>>(qc, qrp, kc, krp, vtb, obuf);
  gemm_bt<true><<<dim3(16, 32), 256, 0, stream>>>(obuf, wo, d_out, 4096, 2048, 2048);
}